// Round 2
// baseline (462.682 us; speedup 1.0000x reference)
//
#include <hip/hip_runtime.h>
#include <stdint.h>

#define SEQ   2048
#define BATCH 4
#define NH    16
#define HD    64
#define H     1024
#define QKVN  3072

typedef unsigned short u16;
typedef unsigned int   u32;
typedef __bf16 bf16x8 __attribute__((ext_vector_type(8)));
typedef float  f32x4  __attribute__((ext_vector_type(4)));

#define MFMA16(a, b, c) __builtin_amdgcn_mfma_f32_16x16x32_bf16((a), (b), (c), 0, 0, 0)

__device__ __forceinline__ u16 f2bf(float f) {
  u32 u = __float_as_uint(f);
  u = (u + 0x7fffu + ((u >> 16) & 1u)) >> 16;   // RNE
  return (u16)u;
}

// async global->LDS, 16B per lane. LDS dest is WAVE-UNIFORM base + lane*16
// (m104); global src is per-lane. __syncthreads() drains vmcnt -> visible.
__device__ __forceinline__ void gload16(const u16* g, u16* l) {
  __builtin_amdgcn_global_load_lds(
      (const __attribute__((address_space(1))) u32*)g,
      (__attribute__((address_space(3))) u32*)l, 16, 0, 0);
}

// ---------------- fused fp32 -> bf16 casts (one launch) ----------------
// region 0: hidden 2,097,152 float4; regions 1-4: Wq/Wk/Wv/Wo 262,144 each.
__global__ __launch_bounds__(256) void cast_all(
    const float* __restrict__ hid, const float* __restrict__ wq,
    const float* __restrict__ wk,  const float* __restrict__ wv,
    const float* __restrict__ wo,
    u16* __restrict__ hb, u16* __restrict__ wqkv, u16* __restrict__ wo_b)
{
  int i = blockIdx.x * 256 + threadIdx.x;
  const float* s; u16* d; int idx;
  if (i < 2097152) { s = hid; d = hb; idx = i; }
  else {
    int j = i - 2097152;
    int w = j >> 18; idx = j & 262143;
    if      (w == 0) { s = wq; d = wqkv; }
    else if (w == 1) { s = wk; d = wqkv + 1048576; }
    else if (w == 2) { s = wv; d = wqkv + 2097152; }
    else             { s = wo; d = wo_b; }
  }
  float4 v = ((const float4*)s)[idx];
  ushort4 o;
  o.x = f2bf(v.x); o.y = f2bf(v.y); o.z = f2bf(v.z); o.w = f2bf(v.w);
  ((ushort4*)d)[idx] = o;
}

// ---------------- bf16 NT GEMM: C[m,n] = sum_k A[m,k]*B[n,k] (+epilogue) ----
// m97 structure: 128x128 tile, BK=32, 4 waves (each 64x64 = 4x4 MFMA frags),
// global_load_lds width-16 staging into LINEAR [128][32] LDS (no swizzle:
// T2 is NULL in 2-phase structures), 2 barriers per K-step.
// EPI=0: outb[m*ldc+n] = bf16(acc + bias_qkv[n])   (bias selected by n/1024)
// EPI=1: outf[m*ldc+n] = acc + b0[n] + resid[m*ldc+n]
template<int EPI>
__global__ __launch_bounds__(256, 2) void gemm_bf16(
    const u16* __restrict__ A, const u16* __restrict__ B,
    u16* __restrict__ outb, float* __restrict__ outf, int ldc,
    const float* __restrict__ b0, const float* __restrict__ b1,
    const float* __restrict__ b2, const float* __restrict__ resid)
{
  __shared__ __align__(16) u16 As[128 * 32];
  __shared__ __align__(16) u16 Bs[128 * 32];
  const int tid = threadIdx.x;
  const int lane = tid & 63;
  const int wv = tid >> 6, wr = wv >> 1, wc = wv & 1;
  const int l15 = lane & 15, l4 = lane >> 4;

  // XCD-aware bijective swizzle (nwg % 8 == 0 for both call sites)
  const int nwg = gridDim.x * gridDim.y;
  const int flat = blockIdx.y * gridDim.x + blockIdx.x;
  const int swz = (flat & 7) * (nwg >> 3) + (flat >> 3);
  const int row0 = (swz / gridDim.x) * 128, col0 = (swz % gridDim.x) * 128;

  const f32x4 fz = {0.f, 0.f, 0.f, 0.f};
  f32x4 acc[4][4];
#pragma unroll
  for (int i = 0; i < 4; ++i)
#pragma unroll
    for (int j = 0; j < 4; ++j) acc[i][j] = fz;

  // per-lane source coords for the 1KB staging chunks: 16 rows x 32 cols each
  const int srow = lane >> 2;           // 0..15
  const int skol = (lane & 3) * 8;      // u16 col 0/8/16/24
  const u16* Ab = A + (size_t)(row0 + srow) * 1024 + skol;
  const u16* Bb = B + (size_t)(col0 + srow) * 1024 + skol;
  const int c0 = wv * 2;                // this wave's chunk pair

  for (int kt = 0; kt < 1024; kt += 32) {
    gload16(Ab + (size_t)(c0 * 16) * 1024 + kt,       &As[(c0 * 16) * 32]);
    gload16(Ab + (size_t)(c0 * 16 + 16) * 1024 + kt,  &As[(c0 * 16 + 16) * 32]);
    gload16(Bb + (size_t)(c0 * 16) * 1024 + kt,       &Bs[(c0 * 16) * 32]);
    gload16(Bb + (size_t)(c0 * 16 + 16) * 1024 + kt,  &Bs[(c0 * 16 + 16) * 32]);
    __syncthreads();   // drains vmcnt(0): staged tile visible to all waves

    bf16x8 af[4], bfr[4];
#pragma unroll
    for (int f = 0; f < 4; ++f) {
      af[f]  = *(const bf16x8*)&As[(wr * 64 + f * 16 + l15) * 32 + l4 * 8];
      bfr[f] = *(const bf16x8*)&Bs[(wc * 64 + f * 16 + l15) * 32 + l4 * 8];
    }
#pragma unroll
    for (int i = 0; i < 4; ++i)
#pragma unroll
      for (int j = 0; j < 4; ++j)
        acc[i][j] = MFMA16(af[i], bfr[j], acc[i][j]);
    __syncthreads();   // all reads done before next iteration's gload writes
  }

  if (EPI == 0) {
    const float* bias = (col0 < 1024) ? b0 : (col0 < 2048) ? b1 : b2;
#pragma unroll
    for (int i = 0; i < 4; ++i) {
      int gr0 = row0 + wr * 64 + i * 16 + l4 * 4;
#pragma unroll
      for (int j = 0; j < 4; ++j) {
        int gc = col0 + wc * 64 + j * 16 + l15;
        float bv = bias[gc & 1023];
#pragma unroll
        for (int r = 0; r < 4; ++r)
          outb[(size_t)(gr0 + r) * ldc + gc] = f2bf(acc[i][j][r] + bv);
      }
    }
  } else {
#pragma unroll
    for (int i = 0; i < 4; ++i) {
      int gr0 = row0 + wr * 64 + i * 16 + l4 * 4;
#pragma unroll
      for (int j = 0; j < 4; ++j) {
        int gc = col0 + wc * 64 + j * 16 + l15;
        float bv = b0[gc];
#pragma unroll
        for (int r = 0; r < 4; ++r) {
          size_t idx = (size_t)(gr0 + r) * ldc + gc;
          outf[idx] = acc[i][j][r] + bv + resid[idx];
        }
      }
    }
  }
}

// ---------------- flash attention (bf16 MFMA, online softmax) ----------------
// 1024 blocks (16 qtiles x 16 heads x 4 batch), 256 thr = 4 waves, 32 q-rows
// each. Reg-staged K/V with +8-u16 row pad (gload_lds would force linear
// 128B rows = 32-way ds_read conflict, G4).
__global__ __launch_bounds__(256, 2) void flash_attn(
    const u16* __restrict__ qkv, const float* __restrict__ mask,
    u16* __restrict__ ctxb)
{
  __shared__ __align__(16) u16 PQs[128 * 72];  // Q staging, then P (wave-private rows)
  __shared__ __align__(16) u16 Ks[64 * 72];
  __shared__ __align__(16) u16 Vt[64 * 72];    // V transposed: Vt[d][kv]

  // XCD swizzle: keep the 16 q-tile blocks sharing one (b,h) KV panel on one XCD
  const int flat = (blockIdx.z * 16 + blockIdx.y) * 16 + blockIdx.x;  // 1024
  const int swzb = (flat & 7) * 128 + (flat >> 3);
  const int qt = swzb & 15, h = (swzb >> 4) & 15, b = swzb >> 8;

  const int tid = threadIdx.x, lane = tid & 63, wv = tid >> 6;
  const int l15 = lane & 15, l4 = lane >> 4;

  const size_t tokb = (size_t)b * SEQ;
  const u16* Qg = qkv + (tokb + (size_t)qt * 128) * QKVN + h * HD;
  const u16* Kg = qkv + tokb * QKVN + 1024 + h * HD;
  const u16* Vg = qkv + tokb * QKVN + 2048 + h * HD;
  const float* maskp = mask + (size_t)b * SEQ;

  // stage Q tile [128][64] -> PQs
#pragma unroll
  for (int cc = 0; cc < 4; ++cc) {
    int c = tid + cc * 256;
    int r = c >> 3, ko = (c & 7) * 8;
    *(uint4*)&PQs[r * 72 + ko] = *(const uint4*)&Qg[(size_t)r * QKVN + ko];
  }
  __syncthreads();
  bf16x8 qf[2][2];
#pragma unroll
  for (int qfi = 0; qfi < 2; ++qfi)
#pragma unroll
    for (int ka = 0; ka < 2; ++ka)
      qf[qfi][ka] = *(const bf16x8*)&PQs[(wv * 32 + qfi * 16 + l15) * 72 + ka * 32 + l4 * 8];

  const f32x4 fz = {0.f, 0.f, 0.f, 0.f};
  float m_run[2][4], l_run[2][4];
  f32x4 ctx[2][4];
#pragma unroll
  for (int qfi = 0; qfi < 2; ++qfi)
#pragma unroll
    for (int r = 0; r < 4; ++r) { m_run[qfi][r] = -1e30f; l_run[qfi][r] = 0.f; }
#pragma unroll
  for (int qfi = 0; qfi < 2; ++qfi)
#pragma unroll
    for (int d = 0; d < 4; ++d) ctx[qfi][d] = fz;

  for (int kv0 = 0; kv0 < SEQ; kv0 += 64) {
    // stage K [64][64] and V^T [64(d)][64(kv)]
#pragma unroll
    for (int cc = 0; cc < 2; ++cc) {
      int c = tid + cc * 256;
      int r = c >> 3, ko = (c & 7) * 8;
      *(uint4*)&Ks[r * 72 + ko] = *(const uint4*)&Kg[(size_t)(kv0 + r) * QKVN + ko];
      uint4 vv = *(const uint4*)&Vg[(size_t)(kv0 + r) * QKVN + ko];
      const u16* pv = (const u16*)&vv;
#pragma unroll
      for (int i = 0; i < 8; ++i) Vt[(ko + i) * 72 + r] = pv[i];
    }
    __syncthreads();

    // scores: S = (Q K^T)/8 + mask   (D-layout: row q = l4*4+r, col kv = l15)
    f32x4 s[2][4];
#pragma unroll
    for (int nch = 0; nch < 4; ++nch) {
      bf16x8 kf0 = *(const bf16x8*)&Ks[(nch * 16 + l15) * 72 + l4 * 8];
      bf16x8 kf1 = *(const bf16x8*)&Ks[(nch * 16 + l15) * 72 + 32 + l4 * 8];
#pragma unroll
      for (int qfi = 0; qfi < 2; ++qfi) {
        f32x4 a = fz;
        a = MFMA16(qf[qfi][0], kf0, a);
        a = MFMA16(qf[qfi][1], kf1, a);
        s[qfi][nch] = a;
      }
    }
    float mv[4];
#pragma unroll
    for (int nch = 0; nch < 4; ++nch) mv[nch] = maskp[kv0 + nch * 16 + l15];
#pragma unroll
    for (int qfi = 0; qfi < 2; ++qfi)
#pragma unroll
      for (int nch = 0; nch < 4; ++nch)
#pragma unroll
        for (int r = 0; r < 4; ++r)
          s[qfi][nch][r] = s[qfi][nch][r] * 0.125f + mv[nch];

    // online softmax per 16-row frag (rows live in 16-lane groups)
#pragma unroll
    for (int qfi = 0; qfi < 2; ++qfi) {
      float mx[4], rs[4];
#pragma unroll
      for (int r = 0; r < 4; ++r)
        mx[r] = fmaxf(fmaxf(s[qfi][0][r], s[qfi][1][r]), fmaxf(s[qfi][2][r], s[qfi][3][r]));
#pragma unroll
      for (int d = 1; d < 16; d <<= 1)
#pragma unroll
        for (int r = 0; r < 4; ++r) mx[r] = fmaxf(mx[r], __shfl_xor(mx[r], d));
#pragma unroll
      for (int r = 0; r < 4; ++r) {
        float mn = fmaxf(m_run[qfi][r], mx[r]);
        float al = __expf(m_run[qfi][r] - mn);
        m_run[qfi][r] = mn;
        l_run[qfi][r] *= al;
#pragma unroll
        for (int d = 0; d < 4; ++d) ctx[qfi][d][r] *= al;
        rs[r] = 0.f;
      }
#pragma unroll
      for (int nch = 0; nch < 4; ++nch)
#pragma unroll
        for (int r = 0; r < 4; ++r) {
          float p = __expf(s[qfi][nch][r] - m_run[qfi][r]);
          rs[r] += p;
          PQs[(wv * 32 + qfi * 16 + l4 * 4 + r) * 72 + nch * 16 + l15] = f2bf(p);
        }
#pragma unroll
      for (int d = 1; d < 16; d <<= 1)
#pragma unroll
        for (int r = 0; r < 4; ++r) rs[r] += __shfl_xor(rs[r], d);
#pragma unroll
      for (int r = 0; r < 4; ++r) l_run[qfi][r] += rs[r];
    }
    // wave-internal LDS write->read fence (P rows are wave-private; one wave's
    // writes are drained by its own lgkmcnt; "memory" blocks compiler reorder)
    asm volatile("s_waitcnt lgkmcnt(0)" ::: "memory");

    // PV: ctx += P V
#pragma unroll
    for (int qfi = 0; qfi < 2; ++qfi) {
      bf16x8 pa0 = *(const bf16x8*)&PQs[(wv * 32 + qfi * 16 + l15) * 72 + l4 * 8];
      bf16x8 pa1 = *(const bf16x8*)&PQs[(wv * 32 + qfi * 16 + l15) * 72 + 32 + l4 * 8];
#pragma unroll
      for (int d = 0; d < 4; ++d) {
        bf16x8 vf0 = *(const bf16x8*)&Vt[(d * 16 + l15) * 72 + l4 * 8];
        bf16x8 vf1 = *(const bf16x8*)&Vt[(d * 16 + l15) * 72 + 32 + l4 * 8];
        ctx[qfi][d] = MFMA16(pa0, vf0, ctx[qfi][d]);
        ctx[qfi][d] = MFMA16(pa1, vf1, ctx[qfi][d]);
      }
    }
    __syncthreads();  // protect Ks/Vt before next stage
  }

  // normalize + write ctx (token-major [8192][1024] bf16)
#pragma unroll
  for (int qfi = 0; qfi < 2; ++qfi)
#pragma unroll
    for (int d = 0; d < 4; ++d)
#pragma unroll
      for (int r = 0; r < 4; ++r) {
        int gr = qt * 128 + wv * 32 + qfi * 16 + l4 * 4 + r;
        float o = ctx[qfi][d][r] / l_run[qfi][r];
        ctxb[(tokb + gr) * (size_t)H + h * HD + d * 16 + l15] = f2bf(o);
      }
}

// ---------------- residual LayerNorm ----------------
__global__ __launch_bounds__(256) void ln_res(const float* __restrict__ x,
    const float* __restrict__ gamma, const float* __restrict__ beta,
    float* __restrict__ out)
{
  const int row = blockIdx.x, t = threadIdx.x;
  float4 v = ((const float4*)(x + (size_t)row * H))[t];
  float s1 = v.x + v.y + v.z + v.w;
  float s2 = v.x * v.x + v.y * v.y + v.z * v.z + v.w * v.w;
#pragma unroll
  for (int d = 1; d < 64; d <<= 1) { s1 += __shfl_xor(s1, d); s2 += __shfl_xor(s2, d); }
  __shared__ float a1[4], a2[4];
  if ((t & 63) == 0) { a1[t >> 6] = s1; a2[t >> 6] = s2; }
  __syncthreads();
  s1 = a1[0] + a1[1] + a1[2] + a1[3];
  s2 = a2[0] + a2[1] + a2[2] + a2[3];
  float mu  = s1 * (1.f / H);
  float var = s2 * (1.f / H) - mu * mu;
  float rstd = rsqrtf(var + 1e-12f);
  float4 g  = ((const float4*)gamma)[t];
  float4 be = ((const float4*)beta)[t];
  float4 o;
  o.x = (v.x - mu) * rstd * g.x + be.x;
  o.y = (v.y - mu) * rstd * g.y + be.y;
  o.z = (v.z - mu) * rstd * g.z + be.z;
  o.w = (v.w - mu) * rstd * g.w + be.w;
  ((float4*)(out + (size_t)row * H))[t] = o;
}

// ---------------- launch ----------------
extern "C" void kernel_launch(void* const* d_in, const int* in_sizes, int n_in,
                              void* d_out, int out_size, void* d_ws, size_t ws_size,
                              hipStream_t stream)
{
  const float* hid  = (const float*)d_in[0];
  const float* mask = (const float*)d_in[1];
  const float* Wq   = (const float*)d_in[2];
  const float* bq   = (const float*)d_in[3];
  const float* Wk   = (const float*)d_in[4];
  const float* bk   = (const float*)d_in[5];
  const float* Wv   = (const float*)d_in[6];
  const float* bv   = (const float*)d_in[7];
  const float* Wo   = (const float*)d_in[8];
  const float* bo   = (const float*)d_in[9];
  const float* gam  = (const float*)d_in[10];
  const float* bet  = (const float*)d_in[11];

  // ws layout (92.3 MB total):
  char* ws = (char*)d_ws;
  u16*   hb   = (u16*)(ws);               // hidden bf16   [8192][1024]  16,777,216 B
  u16*   wqkv = (u16*)(ws + 16777216);    // Wq|Wk|Wv bf16 [3072][1024]   6,291,456 B
  u16*   wo_b = (u16*)(ws + 23068672);    // Wo bf16       [1024][1024]   2,097,152 B
  u16*   qkvb = (u16*)(ws + 25165824);    // QKV bf16      [8192][3072]  50,331,648 B
  u16*   ctxb = (u16*)(ws + 75497472);    // ctx bf16      [8192][1024]  16,777,216 B
  float* tmp  = (float*)(ws + 25165824);  // overlays qkvb (dead after attention)

  cast_all<<<12288, 256, 0, stream>>>(hid, Wq, Wk, Wv, Wo, hb, wqkv, wo_b);

  gemm_bf16<0><<<dim3(24, 64), 256, 0, stream>>>(hb, wqkv, qkvb, nullptr, QKVN,
                                                 bq, bk, bv, nullptr);
  flash_attn<<<dim3(16, NH, BATCH), 256, 0, stream>>>(qkvb, mask, ctxb);
  gemm_bf16<1><<<dim3(8, 64), 256, 0, stream>>>(ctxb, wo_b, nullptr, tmp, H,
                                                bo, nullptr, nullptr, hid);
  ln_res<<<8192, 256, 0, stream>>>(tmp, gam, bet, (float*)d_out);
}

// Round 3
// 434.385 us; speedup vs baseline: 1.0651x; 1.0651x over previous
//
#include <hip/hip_runtime.h>
#include <stdint.h>

#define SEQ   2048
#define BATCH 4
#define NH    16
#define HD    64
#define H     1024
#define QKVN  3072

typedef unsigned short u16;
typedef unsigned int   u32;
typedef __bf16 bf16x8 __attribute__((ext_vector_type(8)));
typedef float  f32x4  __attribute__((ext_vector_type(4)));
typedef unsigned int v2u  __attribute__((ext_vector_type(2)));
typedef unsigned int u32x4 __attribute__((ext_vector_type(4)));

#define MFMA16(a, b, c) __builtin_amdgcn_mfma_f32_16x16x32_bf16((a), (b), (c), 0, 0, 0)
#define LOG2E 1.4426950408889634f

__device__ __forceinline__ u16 f2bf(float f) {
  u32 u = __float_as_uint(f);
  u = (u + 0x7fffu + ((u >> 16) & 1u)) >> 16;   // RNE
  return (u16)u;
}

// async global->LDS, 16B per lane. LDS dest is WAVE-UNIFORM base + lane*16
// (m104); global src is per-lane. __syncthreads() drains vmcnt -> visible.
__device__ __forceinline__ void gload16(const u16* g, u16* l) {
  __builtin_amdgcn_global_load_lds(
      (const __attribute__((address_space(1))) u32*)g,
      (__attribute__((address_space(3))) u32*)l, 16, 0, 0);
}

__device__ __forceinline__ u32 lds_addr(const void* p) {
  return (u32)(uintptr_t)(const __attribute__((address_space(3))) void*)p;
}

// ---------------- fused fp32 -> bf16 casts (one launch) ----------------
__global__ __launch_bounds__(256) void cast_all(
    const float* __restrict__ hid, const float* __restrict__ wq,
    const float* __restrict__ wk,  const float* __restrict__ wv,
    const float* __restrict__ wo,
    u16* __restrict__ hb, u16* __restrict__ wqkv, u16* __restrict__ wo_b)
{
  int i = blockIdx.x * 256 + threadIdx.x;
  const float* s; u16* d; int idx;
  if (i < 2097152) { s = hid; d = hb; idx = i; }
  else {
    int j = i - 2097152;
    int w = j >> 18; idx = j & 262143;
    if      (w == 0) { s = wq; d = wqkv; }
    else if (w == 1) { s = wk; d = wqkv + 1048576; }
    else if (w == 2) { s = wv; d = wqkv + 2097152; }
    else             { s = wo; d = wo_b; }
  }
  float4 v = ((const float4*)s)[idx];
  ushort4 o;
  o.x = f2bf(v.x); o.y = f2bf(v.y); o.z = f2bf(v.z); o.w = f2bf(v.w);
  ((ushort4*)d)[idx] = o;
}

// ---------------- bf16 NT GEMM (m97 structure, unchanged from R2) ----------
template<int EPI>
__global__ __launch_bounds__(256, 2) void gemm_bf16(
    const u16* __restrict__ A, const u16* __restrict__ B,
    u16* __restrict__ outb, float* __restrict__ outf, int ldc,
    const float* __restrict__ b0, const float* __restrict__ b1,
    const float* __restrict__ b2, const float* __restrict__ resid)
{
  __shared__ __align__(16) u16 As[128 * 32];
  __shared__ __align__(16) u16 Bs[128 * 32];
  const int tid = threadIdx.x;
  const int lane = tid & 63;
  const int wv = tid >> 6, wr = wv >> 1, wc = wv & 1;
  const int l15 = lane & 15, l4 = lane >> 4;

  const int nwg = gridDim.x * gridDim.y;
  const int flat = blockIdx.y * gridDim.x + blockIdx.x;
  const int swz = (flat & 7) * (nwg >> 3) + (flat >> 3);
  const int row0 = (swz / gridDim.x) * 128, col0 = (swz % gridDim.x) * 128;

  const f32x4 fz = {0.f, 0.f, 0.f, 0.f};
  f32x4 acc[4][4];
#pragma unroll
  for (int i = 0; i < 4; ++i)
#pragma unroll
    for (int j = 0; j < 4; ++j) acc[i][j] = fz;

  const int srow = lane >> 2;
  const int skol = (lane & 3) * 8;
  const u16* Ab = A + (size_t)(row0 + srow) * 1024 + skol;
  const u16* Bb = B + (size_t)(col0 + srow) * 1024 + skol;
  const int c0 = wv * 2;

  for (int kt = 0; kt < 1024; kt += 32) {
    gload16(Ab + (size_t)(c0 * 16) * 1024 + kt,       &As[(c0 * 16) * 32]);
    gload16(Ab + (size_t)(c0 * 16 + 16) * 1024 + kt,  &As[(c0 * 16 + 16) * 32]);
    gload16(Bb + (size_t)(c0 * 16) * 1024 + kt,       &Bs[(c0 * 16) * 32]);
    gload16(Bb + (size_t)(c0 * 16 + 16) * 1024 + kt,  &Bs[(c0 * 16 + 16) * 32]);
    __syncthreads();

    bf16x8 af[4], bfr[4];
#pragma unroll
    for (int f = 0; f < 4; ++f) {
      af[f]  = *(const bf16x8*)&As[(wr * 64 + f * 16 + l15) * 32 + l4 * 8];
      bfr[f] = *(const bf16x8*)&Bs[(wc * 64 + f * 16 + l15) * 32 + l4 * 8];
    }
#pragma unroll
    for (int i = 0; i < 4; ++i)
#pragma unroll
      for (int j = 0; j < 4; ++j)
        acc[i][j] = MFMA16(af[i], bfr[j], acc[i][j]);
    __syncthreads();
  }

  if (EPI == 0) {
    const float* bias = (col0 < 1024) ? b0 : (col0 < 2048) ? b1 : b2;
#pragma unroll
    for (int i = 0; i < 4; ++i) {
      int gr0 = row0 + wr * 64 + i * 16 + l4 * 4;
#pragma unroll
      for (int j = 0; j < 4; ++j) {
        int gc = col0 + wc * 64 + j * 16 + l15;
        float bv = bias[gc & 1023];
#pragma unroll
        for (int r = 0; r < 4; ++r)
          outb[(size_t)(gr0 + r) * ldc + gc] = f2bf(acc[i][j][r] + bv);
      }
    }
  } else {
#pragma unroll
    for (int i = 0; i < 4; ++i) {
      int gr0 = row0 + wr * 64 + i * 16 + l4 * 4;
#pragma unroll
      for (int j = 0; j < 4; ++j) {
        int gc = col0 + wc * 64 + j * 16 + l15;
        float bv = b0[gc];
#pragma unroll
        for (int r = 0; r < 4; ++r) {
          size_t idx = (size_t)(gr0 + r) * ldc + gc;
          outf[idx] = acc[i][j][r] + bv + resid[idx];
        }
      }
    }
  }
}

// ---------------- flash attention ----------------
// R3 changes vs R2: (1) V staged ROW-major into [4][64][16] subtiles with
// vectorized writes, consumed via ds_read_b64_tr_b16 (kills the 8-way scatter
// conflicts); (2) T14 async-STAGE split: next tile's K/V global->reg loads
// issued under current tile's compute; (3) exp2-domain softmax + defer-max
// (T13, THR=8*log2e); (4) s_setprio around MFMA clusters (m191: +attn).
__global__ __launch_bounds__(256, 2) void flash_attn(
    const u16* __restrict__ qkv, const float* __restrict__ mask,
    u16* __restrict__ ctxb)
{
  __shared__ __align__(16) u16 PQs[128 * 72];  // Q staging, then P (wave-private rows)
  __shared__ __align__(16) u16 Ks[64 * 72];
  __shared__ __align__(16) u16 Vs[4096];       // [db 0..3][kv 0..63][16 d] row-major subtiles

  const int flat = (blockIdx.z * 16 + blockIdx.y) * 16 + blockIdx.x;
  const int swzb = (flat & 7) * 128 + (flat >> 3);
  const int qt = swzb & 15, h = (swzb >> 4) & 15, b = swzb >> 8;

  const int tid = threadIdx.x, lane = tid & 63, wv = tid >> 6;
  const int l15 = lane & 15, l4 = lane >> 4;

  const size_t tokb = (size_t)b * SEQ;
  const u16* Qg = qkv + (tokb + (size_t)qt * 128) * QKVN + h * HD;
  const u16* Kg = qkv + tokb * QKVN + 1024 + h * HD;
  const u16* Vg = qkv + tokb * QKVN + 2048 + h * HD;
  const float* maskp = mask + (size_t)b * SEQ;

  // stage Q tile [128][64] -> PQs
#pragma unroll
  for (int cc = 0; cc < 4; ++cc) {
    int c = tid + cc * 256;
    int r = c >> 3, ko = (c & 7) * 8;
    *(uint4*)&PQs[r * 72 + ko] = *(const uint4*)&Qg[(size_t)r * QKVN + ko];
  }
  __syncthreads();
  bf16x8 qf[2][2];
#pragma unroll
  for (int qfi = 0; qfi < 2; ++qfi)
#pragma unroll
    for (int ka = 0; ka < 2; ++ka)
      qf[qfi][ka] = *(const bf16x8*)&PQs[(wv * 32 + qfi * 16 + l15) * 72 + ka * 32 + l4 * 8];

  const f32x4 fz = {0.f, 0.f, 0.f, 0.f};
  float m_run[2][4], l_run[2][4];
  f32x4 ctx[2][4];
#pragma unroll
  for (int qfi = 0; qfi < 2; ++qfi)
#pragma unroll
    for (int r = 0; r < 4; ++r) { m_run[qfi][r] = -1e30f; l_run[qfi][r] = 0.f; }
#pragma unroll
  for (int qfi = 0; qfi < 2; ++qfi)
#pragma unroll
    for (int d = 0; d < 4; ++d) ctx[qfi][d] = fz;

  // staging coords: each thread owns rows sr, sr+32 at col chunk sk
  const int sr = tid >> 3, sk = (tid & 7) * 8;      // sr 0..31, sk 0,8,..,56
  const int vso = (sk >> 4) * 1024 + (sk & 15);     // Vs elem offset base
  // per-lane tr-read address (see header comment: group g reads 4x16 subtile)
  const u32 vaddr0 = lds_addr(&Vs[0]) + lane * 8 + (lane >> 4) * 128;

  uint4 kr0, kr1, vr0, vr1;
  kr0 = *(const uint4*)&Kg[(size_t)sr * QKVN + sk];
  kr1 = *(const uint4*)&Kg[(size_t)(sr + 32) * QKVN + sk];
  vr0 = *(const uint4*)&Vg[(size_t)sr * QKVN + sk];
  vr1 = *(const uint4*)&Vg[(size_t)(sr + 32) * QKVN + sk];

  for (int kv0 = 0; kv0 < SEQ; kv0 += 64) {
    // write staged regs -> LDS (K padded row-major; V subtiled row-major)
    *(uint4*)&Ks[sr * 72 + sk]        = kr0;
    *(uint4*)&Ks[(sr + 32) * 72 + sk] = kr1;
    *(uint4*)&Vs[vso + sr * 16]        = vr0;
    *(uint4*)&Vs[vso + (sr + 32) * 16] = vr1;
    __syncthreads();

    // T14: issue next tile's global loads now; latency hides under compute
    if (kv0 + 64 < SEQ) {
      kr0 = *(const uint4*)&Kg[(size_t)(kv0 + 64 + sr) * QKVN + sk];
      kr1 = *(const uint4*)&Kg[(size_t)(kv0 + 96 + sr) * QKVN + sk];
      vr0 = *(const uint4*)&Vg[(size_t)(kv0 + 64 + sr) * QKVN + sk];
      vr1 = *(const uint4*)&Vg[(size_t)(kv0 + 96 + sr) * QKVN + sk];
    }

    // scores: S = (Q K^T) * (log2e/8) + mask*log2e   (exp2 domain)
    f32x4 s[2][4];
    __builtin_amdgcn_s_setprio(1);
#pragma unroll
    for (int nch = 0; nch < 4; ++nch) {
      bf16x8 kf0 = *(const bf16x8*)&Ks[(nch * 16 + l15) * 72 + l4 * 8];
      bf16x8 kf1 = *(const bf16x8*)&Ks[(nch * 16 + l15) * 72 + 32 + l4 * 8];
#pragma unroll
      for (int qfi = 0; qfi < 2; ++qfi) {
        f32x4 a = fz;
        a = MFMA16(qf[qfi][0], kf0, a);
        a = MFMA16(qf[qfi][1], kf1, a);
        s[qfi][nch] = a;
      }
    }
    __builtin_amdgcn_s_setprio(0);
    float mv[4];
#pragma unroll
    for (int nch = 0; nch < 4; ++nch) mv[nch] = maskp[kv0 + nch * 16 + l15] * LOG2E;
#pragma unroll
    for (int qfi = 0; qfi < 2; ++qfi)
#pragma unroll
      for (int nch = 0; nch < 4; ++nch)
#pragma unroll
        for (int r = 0; r < 4; ++r)
          s[qfi][nch][r] = s[qfi][nch][r] * (0.125f * LOG2E) + mv[nch];

    // online softmax (log2 domain) with defer-max (T13)
#pragma unroll
    for (int qfi = 0; qfi < 2; ++qfi) {
      float mx[4], rs[4];
#pragma unroll
      for (int r = 0; r < 4; ++r)
        mx[r] = fmaxf(fmaxf(s[qfi][0][r], s[qfi][1][r]), fmaxf(s[qfi][2][r], s[qfi][3][r]));
#pragma unroll
      for (int d = 1; d < 16; d <<= 1)
#pragma unroll
        for (int r = 0; r < 4; ++r) mx[r] = fmaxf(mx[r], __shfl_xor(mx[r], d));
      bool need = false;
#pragma unroll
      for (int r = 0; r < 4; ++r) need |= (mx[r] > m_run[qfi][r] + 11.5415603f);
      if (__any((int)need)) {
#pragma unroll
        for (int r = 0; r < 4; ++r) {
          float mn = fmaxf(m_run[qfi][r], mx[r]);
          float al = exp2f(m_run[qfi][r] - mn);
          m_run[qfi][r] = mn;
          l_run[qfi][r] *= al;
#pragma unroll
          for (int d = 0; d < 4; ++d) ctx[qfi][d][r] *= al;
        }
      }
#pragma unroll
      for (int r = 0; r < 4; ++r) rs[r] = 0.f;
#pragma unroll
      for (int nch = 0; nch < 4; ++nch)
#pragma unroll
        for (int r = 0; r < 4; ++r) {
          float p = exp2f(s[qfi][nch][r] - m_run[qfi][r]);
          rs[r] += p;
          PQs[(wv * 32 + qfi * 16 + l4 * 4 + r) * 72 + nch * 16 + l15] = f2bf(p);
        }
#pragma unroll
      for (int d = 1; d < 16; d <<= 1)
#pragma unroll
        for (int r = 0; r < 4; ++r) rs[r] += __shfl_xor(rs[r], d);
#pragma unroll
      for (int r = 0; r < 4; ++r) l_run[qfi][r] += rs[r];
    }
    // wave-internal LDS write->read fence (P rows are wave-private)
    asm volatile("s_waitcnt lgkmcnt(0)" ::: "memory");

    // PV: ctx += P V, V via hardware transpose-read (T10)
    bf16x8 pa[2][2];
#pragma unroll
    for (int qfi = 0; qfi < 2; ++qfi) {
      pa[qfi][0] = *(const bf16x8*)&PQs[(wv * 32 + qfi * 16 + l15) * 72 + l4 * 8];
      pa[qfi][1] = *(const bf16x8*)&PQs[(wv * 32 + qfi * 16 + l15) * 72 + 32 + l4 * 8];
    }
    __builtin_amdgcn_s_setprio(1);
#pragma unroll
    for (int d = 0; d < 4; ++d) {
      v2u t0, t1, t2, t3;
      u32 va = vaddr0 + d * 2048;
      asm volatile("ds_read_b64_tr_b16 %0, %1"             : "=&v"(t0) : "v"(va));
      asm volatile("ds_read_b64_tr_b16 %0, %1 offset:128"  : "=&v"(t1) : "v"(va));
      asm volatile("ds_read_b64_tr_b16 %0, %1 offset:1024" : "=&v"(t2) : "v"(va));
      asm volatile("ds_read_b64_tr_b16 %0, %1 offset:1152" : "=&v"(t3) : "v"(va));
      asm volatile("s_waitcnt lgkmcnt(0)");
      __builtin_amdgcn_sched_barrier(0);
      u32x4 w0 = {t0[0], t0[1], t1[0], t1[1]};
      u32x4 w1 = {t2[0], t2[1], t3[0], t3[1]};
      bf16x8 vf0 = __builtin_bit_cast(bf16x8, w0);
      bf16x8 vf1 = __builtin_bit_cast(bf16x8, w1);
      ctx[0][d] = MFMA16(pa[0][0], vf0, ctx[0][d]);
      ctx[0][d] = MFMA16(pa[0][1], vf1, ctx[0][d]);
      ctx[1][d] = MFMA16(pa[1][0], vf0, ctx[1][d]);
      ctx[1][d] = MFMA16(pa[1][1], vf1, ctx[1][d]);
    }
    __builtin_amdgcn_s_setprio(0);
    __syncthreads();  // protect Ks/Vs before next tile's stores
  }

  // normalize + write ctx (token-major [8192][1024] bf16)
#pragma unroll
  for (int qfi = 0; qfi < 2; ++qfi)
#pragma unroll
    for (int d = 0; d < 4; ++d)
#pragma unroll
      for (int r = 0; r < 4; ++r) {
        int gr = qt * 128 + wv * 32 + qfi * 16 + l4 * 4 + r;
        float o = ctx[qfi][d][r] / l_run[qfi][r];
        ctxb[(tokb + gr) * (size_t)H + h * HD + d * 16 + l15] = f2bf(o);
      }
}

// ---------------- residual LayerNorm ----------------
__global__ __launch_bounds__(256) void ln_res(const float* __restrict__ x,
    const float* __restrict__ gamma, const float* __restrict__ beta,
    float* __restrict__ out)
{
  const int row = blockIdx.x, t = threadIdx.x;
  float4 v = ((const float4*)(x + (size_t)row * H))[t];
  float s1 = v.x + v.y + v.z + v.w;
  float s2 = v.x * v.x + v.y * v.y + v.z * v.z + v.w * v.w;
#pragma unroll
  for (int d = 1; d < 64; d <<= 1) { s1 += __shfl_xor(s1, d); s2 += __shfl_xor(s2, d); }
  __shared__ float a1[4], a2[4];
  if ((t & 63) == 0) { a1[t >> 6] = s1; a2[t >> 6] = s2; }
  __syncthreads();
  s1 = a1[0] + a1[1] + a1[2] + a1[3];
  s2 = a2[0] + a2[1] + a2[2] + a2[3];
  float mu  = s1 * (1.f / H);
  float var = s2 * (1.f / H) - mu * mu;
  float rstd = rsqrtf(var + 1e-12f);
  float4 g  = ((const float4*)gamma)[t];
  float4 be = ((const float4*)beta)[t];
  float4 o;
  o.x = (v.x - mu) * rstd * g.x + be.x;
  o.y = (v.y - mu) * rstd * g.y + be.y;
  o.z = (v.z - mu) * rstd * g.z + be.z;
  o.w = (v.w - mu) * rstd * g.w + be.w;
  ((float4*)(out + (size_t)row * H))[t] = o;
}

// ---------------- launch ----------------
extern "C" void kernel_launch(void* const* d_in, const int* in_sizes, int n_in,
                              void* d_out, int out_size, void* d_ws, size_t ws_size,
                              hipStream_t stream)
{
  const float* hid  = (const float*)d_in[0];
  const float* mask = (const float*)d_in[1];
  const float* Wq   = (const float*)d_in[2];
  const float* bq   = (const float*)d_in[3];
  const float* Wk   = (const float*)d_in[4];
  const float* bk   = (const float*)d_in[5];
  const float* Wv   = (const float*)d_in[6];
  const float* bv   = (const float*)d_in[7];
  const float* Wo   = (const float*)d_in[8];
  const float* bo   = (const float*)d_in[9];
  const float* gam  = (const float*)d_in[10];
  const float* bet  = (const float*)d_in[11];

  char* ws = (char*)d_ws;
  u16*   hb   = (u16*)(ws);               // hidden bf16   [8192][1024]
  u16*   wqkv = (u16*)(ws + 16777216);    // Wq|Wk|Wv bf16 [3072][1024]
  u16*   wo_b = (u16*)(ws + 23068672);    // Wo bf16       [1024][1024]
  u16*   qkvb = (u16*)(ws + 25165824);    // QKV bf16      [8192][3072]
  u16*   ctxb = (u16*)(ws + 75497472);    // ctx bf16      [8192][1024]
  float* tmp  = (float*)(ws + 25165824);  // overlays qkvb (dead after attention)

  cast_all<<<12288, 256, 0, stream>>>(hid, Wq, Wk, Wv, Wo, hb, wqkv, wo_b);

  gemm_bf16<0><<<dim3(24, 64), 256, 0, stream>>>(hb, wqkv, qkvb, nullptr, QKVN,
                                                 bq, bk, bv, nullptr);
  flash_attn<<<dim3(16, NH, BATCH), 256, 0, stream>>>(qkvb, mask, ctxb);
  gemm_bf16<1><<<dim3(8, 64), 256, 0, stream>>>(ctxb, wo_b, nullptr, tmp, H,
                                                bo, nullptr, nullptr, hid);
  ln_res<<<8192, 256, 0, stream>>>(tmp, gam, bet, (float*)d_out);
}

// Round 5
// 361.740 us; speedup vs baseline: 1.2790x; 1.2008x over previous
//
#include <hip/hip_runtime.h>
#include <stdint.h>

#define SEQ   2048
#define BATCH 4
#define NH    16
#define HD    64
#define H     1024
#define QKVN  3072

typedef unsigned short u16;
typedef unsigned int   u32;
typedef __bf16 bf16x8 __attribute__((ext_vector_type(8)));
typedef float  f32x4  __attribute__((ext_vector_type(4)));
typedef float  f32x16 __attribute__((ext_vector_type(16)));
typedef unsigned int v2u   __attribute__((ext_vector_type(2)));
typedef unsigned int u32x4 __attribute__((ext_vector_type(4)));

#define MFMA16(a, b, c) __builtin_amdgcn_mfma_f32_16x16x32_bf16((a), (b), (c), 0, 0, 0)
#define MFMA32(a, b, c) __builtin_amdgcn_mfma_f32_32x32x16_bf16((a), (b), (c), 0, 0, 0)
#define LOG2E 1.4426950408889634f
#define SC    (0.125f * LOG2E)

__device__ __forceinline__ u16 f2bf(float f) {
  u32 u = __float_as_uint(f);
  u = (u + 0x7fffu + ((u >> 16) & 1u)) >> 16;   // RNE
  return (u16)u;
}

__device__ __forceinline__ void gload16(const u16* g, u16* l) {
  __builtin_amdgcn_global_load_lds(
      (const __attribute__((address_space(1))) u32*)g,
      (__attribute__((address_space(3))) u32*)l, 16, 0, 0);
}

__device__ __forceinline__ u32 lds_addr(const void* p) {
  return (u32)(uintptr_t)(const __attribute__((address_space(3))) void*)p;
}

__device__ __forceinline__ u32 cvtpk(float lo, float hi) {
  u32 r;
  asm("v_cvt_pk_bf16_f32 %0, %1, %2" : "=v"(r) : "v"(lo), "v"(hi));
  return r;
}

// ---------------- fused fp32 -> bf16 casts ----------------
__global__ __launch_bounds__(256) void cast_all(
    const float* __restrict__ hid, const float* __restrict__ wq,
    const float* __restrict__ wk,  const float* __restrict__ wv,
    const float* __restrict__ wo,
    u16* __restrict__ hb, u16* __restrict__ wqkv, u16* __restrict__ wo_b)
{
  int i = blockIdx.x * 256 + threadIdx.x;
  const float* s; u16* d; int idx;
  if (i < 2097152) { s = hid; d = hb; idx = i; }
  else {
    int j = i - 2097152;
    int w = j >> 18; idx = j & 262143;
    if      (w == 0) { s = wq; d = wqkv; }
    else if (w == 1) { s = wk; d = wqkv + 1048576; }
    else if (w == 2) { s = wv; d = wqkv + 2097152; }
    else             { s = wo; d = wo_b; }
  }
  float4 v = ((const float4*)s)[idx];
  ushort4 o;
  o.x = f2bf(v.x); o.y = f2bf(v.y); o.z = f2bf(v.z); o.w = f2bf(v.w);
  ((ushort4*)d)[idx] = o;
}

// ---------------- bf16 NT GEMM (m97 structure, unchanged) ----------
template<int EPI>
__global__ __launch_bounds__(256, 2) void gemm_bf16(
    const u16* __restrict__ A, const u16* __restrict__ B,
    u16* __restrict__ outb, float* __restrict__ outf, int ldc,
    const float* __restrict__ b0, const float* __restrict__ b1,
    const float* __restrict__ b2, const float* __restrict__ resid)
{
  __shared__ __align__(16) u16 As[128 * 32];
  __shared__ __align__(16) u16 Bs[128 * 32];
  const int tid = threadIdx.x;
  const int lane = tid & 63;
  const int wv = tid >> 6, wr = wv >> 1, wc = wv & 1;
  const int l15 = lane & 15, l4 = lane >> 4;

  const int nwg = gridDim.x * gridDim.y;
  const int flat = blockIdx.y * gridDim.x + blockIdx.x;
  const int swz = (flat & 7) * (nwg >> 3) + (flat >> 3);
  const int row0 = (swz / gridDim.x) * 128, col0 = (swz % gridDim.x) * 128;

  const f32x4 fz = {0.f, 0.f, 0.f, 0.f};
  f32x4 acc[4][4];
#pragma unroll
  for (int i = 0; i < 4; ++i)
#pragma unroll
    for (int j = 0; j < 4; ++j) acc[i][j] = fz;

  const int srow = lane >> 2;
  const int skol = (lane & 3) * 8;
  const u16* Ab = A + (size_t)(row0 + srow) * 1024 + skol;
  const u16* Bb = B + (size_t)(col0 + srow) * 1024 + skol;
  const int c0 = wv * 2;

  for (int kt = 0; kt < 1024; kt += 32) {
    gload16(Ab + (size_t)(c0 * 16) * 1024 + kt,       &As[(c0 * 16) * 32]);
    gload16(Ab + (size_t)(c0 * 16 + 16) * 1024 + kt,  &As[(c0 * 16 + 16) * 32]);
    gload16(Bb + (size_t)(c0 * 16) * 1024 + kt,       &Bs[(c0 * 16) * 32]);
    gload16(Bb + (size_t)(c0 * 16 + 16) * 1024 + kt,  &Bs[(c0 * 16 + 16) * 32]);
    __syncthreads();

    bf16x8 af[4], bfr[4];
#pragma unroll
    for (int f = 0; f < 4; ++f) {
      af[f]  = *(const bf16x8*)&As[(wr * 64 + f * 16 + l15) * 32 + l4 * 8];
      bfr[f] = *(const bf16x8*)&Bs[(wc * 64 + f * 16 + l15) * 32 + l4 * 8];
    }
#pragma unroll
    for (int i = 0; i < 4; ++i)
#pragma unroll
      for (int j = 0; j < 4; ++j)
        acc[i][j] = MFMA16(af[i], bfr[j], acc[i][j]);
    __syncthreads();
  }

  if (EPI == 0) {
    const float* bias = (col0 < 1024) ? b0 : (col0 < 2048) ? b1 : b2;
#pragma unroll
    for (int i = 0; i < 4; ++i) {
      int gr0 = row0 + wr * 64 + i * 16 + l4 * 4;
#pragma unroll
      for (int j = 0; j < 4; ++j) {
        int gc = col0 + wc * 64 + j * 16 + l15;
        float bv = bias[gc & 1023];
#pragma unroll
        for (int r = 0; r < 4; ++r)
          outb[(size_t)(gr0 + r) * ldc + gc] = f2bf(acc[i][j][r] + bv);
      }
    }
  } else {
#pragma unroll
    for (int i = 0; i < 4; ++i) {
      int gr0 = row0 + wr * 64 + i * 16 + l4 * 4;
#pragma unroll
      for (int j = 0; j < 4; ++j) {
        int gc = col0 + wc * 64 + j * 16 + l15;
        float bv = b0[gc];
#pragma unroll
        for (int r = 0; r < 4; ++r) {
          size_t idx = (size_t)(gr0 + r) * ldc + gc;
          outf[idx] = acc[i][j][r] + bv + resid[idx];
        }
      }
    }
  }
}

// ---------------- flash attention: swapped-QK 32x32, in-register softmax ----
// Wave owns 32 q-rows. S = mfma(A=K, B=Q): lane holds ONE q (col = lane&31)
// and 32 kv values in regs. Softmax in-lane + one shfl_xor(32). P -> A-frag
// via cvt_pk + permlane32_swap (T12). V via ds_read_b64_tr_b16 from subtiled
// LDS (T10). K/Q XOR-swizzled (byte ^= (row&7)<<4). T14 staging split.
__global__ __launch_bounds__(256, 2) void flash_attn(
    const u16* __restrict__ qkv, const float* __restrict__ mask,
    u16* __restrict__ ctxb)
{
  __shared__ __align__(16) u16 Qs[128 * 64];   // swizzled rows
  __shared__ __align__(16) u16 Ks[64 * 64];    // swizzled rows
  __shared__ __align__(16) u16 Vs[4096];       // subtiled: (d>>4)*1024+(kv>>2)*64+(kv&3)*16+(d&15)

  const int flat = (blockIdx.z * 16 + blockIdx.y) * 16 + blockIdx.x;
  const int swzb = (flat & 7) * 128 + (flat >> 3);
  const int qt = swzb & 15, h = (swzb >> 4) & 15, b = swzb >> 8;

  const int tid = threadIdx.x, lane = tid & 63, wq = tid >> 6;
  const int l31 = lane & 31, l15 = lane & 15, h5 = lane >> 5;

  const size_t tokb = (size_t)b * SEQ;
  const u16* Qg = qkv + (tokb + (size_t)qt * 128) * QKVN + h * HD;
  const u16* Kg = qkv + tokb * QKVN + 1024 + h * HD;
  const u16* Vg = qkv + tokb * QKVN + 2048 + h * HD;
  const float* maskp = mask + (size_t)b * SEQ;

  // ---- stage Q [128][64] swizzled ----
#pragma unroll
  for (int cc = 0; cc < 4; ++cc) {
    int c = tid + cc * 256;
    int r = c >> 3, ko = (c & 7) * 8;
    u32 qb = (u32)(r * 128 + ko * 2) ^ ((r & 7) << 4);
    *(uint4*)((char*)Qs + qb) = *(const uint4*)&Qg[(size_t)r * QKVN + ko];
  }
  __syncthreads();

  // per-lane swizzled column bases (row&7 == l31&7 for all frag rows)
  const u32 swzl = (u32)((l31 & 7) << 4);
  u32 cb[4];
#pragma unroll
  for (int kb = 0; kb < 4; ++kb)
    cb[kb] = ((u32)(kb * 32 + h5 * 16)) ^ swzl;

  // Q B-frags (col q = l31, k = 8*h5 + i per 16-k block kb)
  bf16x8 qf[4];
#pragma unroll
  for (int kb = 0; kb < 4; ++kb)
    qf[kb] = *(const bf16x8*)((char*)Qs + (u32)((wq * 32 + l31) * 128) + cb[kb]);

  float m_run = -1e30f, l_run = 0.f;
  f32x16 ctx0 = {}, ctx1 = {};

  // staging coords (each thread: rows sr, sr+32 at col chunk sk)
  const int sr = tid >> 3, sk = (tid & 7) * 8;
  const u32 kwb0 = ((u32)(sr * 128 + sk * 2)) ^ ((sr & 7) << 4);
  const u32 kwb1 = ((u32)((sr + 32) * 128 + sk * 2)) ^ ((sr & 7) << 4);
  const u32 vw0 = (u32)((sk >> 4) * 1024 + (sr >> 2) * 64 + (sr & 3) * 16 + (sk & 15));
  const u32 vw1 = (u32)((sk >> 4) * 1024 + ((sr + 32) >> 2) * 64 + (sr & 3) * 16 + (sk & 15));

  // tr-read per-lane base: window = 128B-aligned(addr), column = (addr&127)>>3
  const u32 vaddr = lds_addr(Vs) + (u32)(l15 * 8 + ((lane >> 4) & 1) * 2048 + h5 * 256);

  uint4 kr0 = *(const uint4*)&Kg[(size_t)sr * QKVN + sk];
  uint4 kr1 = *(const uint4*)&Kg[(size_t)(sr + 32) * QKVN + sk];
  uint4 vr0 = *(const uint4*)&Vg[(size_t)sr * QKVN + sk];
  uint4 vr1 = *(const uint4*)&Vg[(size_t)(sr + 32) * QKVN + sk];

  for (int kv0 = 0; kv0 < SEQ; kv0 += 64) {
    *(uint4*)((char*)Ks + kwb0) = kr0;
    *(uint4*)((char*)Ks + kwb1) = kr1;
    *(uint4*)&Vs[vw0] = vr0;
    *(uint4*)&Vs[vw1] = vr1;
    __syncthreads();

    // T14: next tile's global loads issue now, land next iteration
    if (kv0 + 64 < SEQ) {
      kr0 = *(const uint4*)&Kg[(size_t)(kv0 + 64 + sr) * QKVN + sk];
      kr1 = *(const uint4*)&Kg[(size_t)(kv0 + 96 + sr) * QKVN + sk];
      vr0 = *(const uint4*)&Vg[(size_t)(kv0 + 64 + sr) * QKVN + sk];
      vr1 = *(const uint4*)&Vg[(size_t)(kv0 + 96 + sr) * QKVN + sk];
    }

    // ---- QK^T swapped: s = K_tile x Q^T, D[kv][q] ----
    f32x16 s0 = {}, s1 = {};
    __builtin_amdgcn_s_setprio(1);
#pragma unroll
    for (int kb = 0; kb < 4; ++kb) {
      bf16x8 a0 = *(const bf16x8*)((char*)Ks + (u32)(l31 * 128) + cb[kb]);
      bf16x8 a1 = *(const bf16x8*)((char*)Ks + (u32)(l31 * 128 + 4096) + cb[kb]);
      s0 = MFMA32(a0, qf[kb], s0);
      s1 = MFMA32(a1, qf[kb], s1);
    }
    __builtin_amdgcn_s_setprio(0);

    // ---- scale + mask (kv = (r&3)+8*(r>>2)+4*h5 + 32*acc) ----
#pragma unroll
    for (int r = 0; r < 16; ++r) {
      int kvr = kv0 + (r & 3) + 8 * (r >> 2);
      float ma = maskp[kvr],      mb = maskp[kvr + 4];
      float mc = maskp[kvr + 32], md = maskp[kvr + 36];
      float mv0 = (h5 ? mb : ma) * LOG2E;
      float mv1 = (h5 ? md : mc) * LOG2E;
      s0[r] = s0[r] * SC + mv0;
      s1[r] = s1[r] * SC + mv1;
    }

    // ---- in-lane max over 32 kv + cross-half ----
    float mx = s0[0];
#pragma unroll
    for (int r = 1; r < 16; ++r) mx = fmaxf(mx, s0[r]);
#pragma unroll
    for (int r = 0; r < 16; ++r) mx = fmaxf(mx, s1[r]);
    mx = fmaxf(mx, __shfl_xor(mx, 32));

    // defer-max (T13): rescale only if max grew past THR (log2 units)
    bool need = (mx > m_run + 11.5415603f);
    if (__any((int)need)) {
      float mn = fmaxf(m_run, mx);
      float al = exp2f(m_run - mn);
      m_run = mn;
      l_run *= al;
#pragma unroll
      for (int r = 0; r < 16; ++r) {
        float av = __shfl(al, (r & 3) + 8 * (r >> 2) + 4 * h5);
        ctx0[r] *= av;
        ctx1[r] *= av;
      }
    }

    // ---- exp + sum (in place) ----
    float ps = 0.f;
#pragma unroll
    for (int r = 0; r < 16; ++r) { s0[r] = exp2f(s0[r] - m_run); ps += s0[r]; }
#pragma unroll
    for (int r = 0; r < 16; ++r) { s1[r] = exp2f(s1[r] - m_run); ps += s1[r]; }
    ps += __shfl_xor(ps, 32);
    l_run += ps;

    // ---- P -> bf16 A-frags (T12): 4 cvt_pk + 2 permlane32_swap per 16-kv ----
    bf16x8 paf[4];
#pragma unroll
    for (int blk = 0; blk < 4; ++blk) {
      u32 w0, w1, w2, w3;
      if (blk < 2) {
        int r0 = blk * 8;
        w0 = cvtpk(s0[r0 + 0], s0[r0 + 1]); w1 = cvtpk(s0[r0 + 2], s0[r0 + 3]);
        w2 = cvtpk(s0[r0 + 4], s0[r0 + 5]); w3 = cvtpk(s0[r0 + 6], s0[r0 + 7]);
      } else {
        int r0 = (blk - 2) * 8;
        w0 = cvtpk(s1[r0 + 0], s1[r0 + 1]); w1 = cvtpk(s1[r0 + 2], s1[r0 + 3]);
        w2 = cvtpk(s1[r0 + 4], s1[r0 + 5]); w3 = cvtpk(s1[r0 + 6], s1[r0 + 7]);
      }
      asm volatile("v_permlane32_swap_b32 %0, %1" : "+v"(w0), "+v"(w2));
      asm volatile("v_permlane32_swap_b32 %0, %1" : "+v"(w1), "+v"(w3));
      u32x4 ww = {w0, w1, w2, w3};
      paf[blk] = __builtin_bit_cast(bf16x8, ww);
    }

    // ---- PV: ctx[db] += P * V, V via tr-read (B-frag: col d = l31, k = kv) --
    __builtin_amdgcn_s_setprio(1);
#pragma unroll
    for (int db = 0; db < 2; ++db) {
      v2u t[8];
#pragma unroll
      for (int kb = 0; kb < 4; ++kb) {
        asm volatile("ds_read_b64_tr_b16 %0, %1 offset:%c2"
                     : "=&v"(t[kb * 2])     : "v"(vaddr), "i"(db * 4096 + kb * 512));
        asm volatile("ds_read_b64_tr_b16 %0, %1 offset:%c2"
                     : "=&v"(t[kb * 2 + 1]) : "v"(vaddr), "i"(db * 4096 + kb * 512 + 128));
      }
      asm volatile("s_waitcnt lgkmcnt(0)");
      __builtin_amdgcn_sched_barrier(0);
#pragma unroll
      for (int kb = 0; kb < 4; ++kb) {
        u32x4 ww = {t[kb * 2][0], t[kb * 2][1], t[kb * 2 + 1][0], t[kb * 2 + 1][1]};
        bf16x8 vf = __builtin_bit_cast(bf16x8, ww);
        if (db == 0) ctx0 = MFMA32(paf[kb], vf, ctx0);
        else         ctx1 = MFMA32(paf[kb], vf, ctx1);
      }
    }
    __builtin_amdgcn_s_setprio(0);
    __syncthreads();  // protect Ks/Vs before next tile's LDS writes
  }

  // ---- normalize + write (ctx D-layout: col d = l31, row q = (r&3)+8*(r>>2)+4*h5)
  float linv = 1.0f / l_run;
#pragma unroll
  for (int r = 0; r < 16; ++r) {
    int qidx = (r & 3) + 8 * (r >> 2) + 4 * h5;
    float li = __shfl(linv, qidx);
    int gr = qt * 128 + wq * 32 + qidx;
    u16* o = &ctxb[(tokb + gr) * (size_t)H + h * HD + l31];
    o[0]  = f2bf(ctx0[r] * li);
    o[32] = f2bf(ctx1[r] * li);
  }
}

// ---------------- residual LayerNorm ----------------
__global__ __launch_bounds__(256) void ln_res(const float* __restrict__ x,
    const float* __restrict__ gamma, const float* __restrict__ beta,
    float* __restrict__ out)
{
  const int row = blockIdx.x, t = threadIdx.x;
  float4 v = ((const float4*)(x + (size_t)row * H))[t];
  float s1 = v.x + v.y + v.z + v.w;
  float s2 = v.x * v.x + v.y * v.y + v.z * v.z + v.w * v.w;
#pragma unroll
  for (int d = 1; d < 64; d <<= 1) { s1 += __shfl_xor(s1, d); s2 += __shfl_xor(s2, d); }
  __shared__ float a1[4], a2[4];
  if ((t & 63) == 0) { a1[t >> 6] = s1; a2[t >> 6] = s2; }
  __syncthreads();
  s1 = a1[0] + a1[1] + a1[2] + a1[3];
  s2 = a2[0] + a2[1] + a2[2] + a2[3];
  float mu  = s1 * (1.f / H);
  float var = s2 * (1.f / H) - mu * mu;
  float rstd = rsqrtf(var + 1e-12f);
  float4 g  = ((const float4*)gamma)[t];
  float4 be = ((const float4*)beta)[t];
  float4 o;
  o.x = (v.x - mu) * rstd * g.x + be.x;
  o.y = (v.y - mu) * rstd * g.y + be.y;
  o.z = (v.z - mu) * rstd * g.z + be.z;
  o.w = (v.w - mu) * rstd * g.w + be.w;
  ((float4*)(out + (size_t)row * H))[t] = o;
}

// ---------------- launch ----------------
extern "C" void kernel_launch(void* const* d_in, const int* in_sizes, int n_in,
                              void* d_out, int out_size, void* d_ws, size_t ws_size,
                              hipStream_t stream)
{
  const float* hid  = (const float*)d_in[0];
  const float* mask = (const float*)d_in[1];
  const float* Wq   = (const float*)d_in[2];
  const float* bq   = (const float*)d_in[3];
  const float* Wk   = (const float*)d_in[4];
  const float* bk   = (const float*)d_in[5];
  const float* Wv   = (const float*)d_in[6];
  const float* bv   = (const float*)d_in[7];
  const float* Wo   = (const float*)d_in[8];
  const float* bo   = (const float*)d_in[9];
  const float* gam  = (const float*)d_in[10];
  const float* bet  = (const float*)d_in[11];

  char* ws = (char*)d_ws;
  u16*   hb   = (u16*)(ws);               // hidden bf16   [8192][1024]
  u16*   wqkv = (u16*)(ws + 16777216);    // Wq|Wk|Wv bf16 [3072][1024]
  u16*   wo_b = (u16*)(ws + 23068672);    // Wo bf16       [1024][1024]
  u16*   qkvb = (u16*)(ws + 25165824);    // QKV bf16      [8192][3072]
  u16*   ctxb = (u16*)(ws + 75497472);    // ctx bf16      [8192][1024]
  float* tmp  = (float*)(ws + 25165824);  // overlays qkvb (dead after attention)

  cast_all<<<12288, 256, 0, stream>>>(hid, Wq, Wk, Wv, Wo, hb, wqkv, wo_b);

  gemm_bf16<0><<<dim3(24, 64), 256, 0, stream>>>(hb, wqkv, qkvb, nullptr, QKVN,
                                                 bq, bk, bv, nullptr);
  flash_attn<<<dim3(16, NH, BATCH), 256, 0, stream>>>(qkvb, mask, ctxb);
  gemm_bf16<1><<<dim3(8, 64), 256, 0, stream>>>(ctxb, wo_b, nullptr, tmp, H,
                                                bo, nullptr, nullptr, hid);
  ln_res<<<8192, 256, 0, stream>>>(tmp, gam, bet, (float*)d_out);
}

// Round 7
// 349.704 us; speedup vs baseline: 1.3231x; 1.0344x over previous
//
#include <hip/hip_runtime.h>
#include <stdint.h>

#define SEQ   2048
#define BATCH 4
#define NH    16
#define HD    64
#define H     1024
#define QKVN  3072

typedef unsigned short u16;
typedef unsigned int   u32;
typedef __bf16 bf16x8 __attribute__((ext_vector_type(8)));
typedef float  f32x4  __attribute__((ext_vector_type(4)));
typedef float  f32x16 __attribute__((ext_vector_type(16)));
typedef unsigned int v2u   __attribute__((ext_vector_type(2)));
typedef unsigned int u32x4 __attribute__((ext_vector_type(4)));

#define MFMA16(a, b, c) __builtin_amdgcn_mfma_f32_16x16x32_bf16((a), (b), (c), 0, 0, 0)
#define MFMA32(a, b, c) __builtin_amdgcn_mfma_f32_32x32x16_bf16((a), (b), (c), 0, 0, 0)
#define LOG2E 1.4426950408889634f
#define SC    (0.125f * LOG2E)

__device__ __forceinline__ u16 f2bf(float f) {
  u32 u = __float_as_uint(f);
  u = (u + 0x7fffu + ((u >> 16) & 1u)) >> 16;   // RNE
  return (u16)u;
}

__device__ __forceinline__ void gload16(const u16* g, u16* l) {
  __builtin_amdgcn_global_load_lds(
      (const __attribute__((address_space(1))) u32*)g,
      (__attribute__((address_space(3))) u32*)l, 16, 0, 0);
}

__device__ __forceinline__ u32 lds_addr(const void* p) {
  return (u32)(uintptr_t)(const __attribute__((address_space(3))) void*)p;
}

__device__ __forceinline__ u32 cvtpk(float lo, float hi) {
  u32 r;
  asm("v_cvt_pk_bf16_f32 %0, %1, %2" : "=v"(r) : "v"(lo), "v"(hi));
  return r;
}

// ---------------- fused fp32 -> bf16 casts + mask->mexp precompute ---------
// regions: [0, 2097152) hidden f4; [.., +1048576) weights f4;
// [.., +2048) mask f4 -> mexpf (f32) + mexpb (bf16), mexp = exp2(mask*log2e).
__global__ __launch_bounds__(256) void cast_all(
    const float* __restrict__ hid, const float* __restrict__ wq,
    const float* __restrict__ wk,  const float* __restrict__ wv,
    const float* __restrict__ wo,  const float* __restrict__ mask,
    u16* __restrict__ hb, u16* __restrict__ wqkv, u16* __restrict__ wo_b,
    float* __restrict__ mexpf, u16* __restrict__ mexpb)
{
  int i = blockIdx.x * 256 + threadIdx.x;
  if (i >= 3145728) {                       // mask region
    int j = i - 3145728;                    // 0..2047
    float4 mv = ((const float4*)mask)[j];
    float4 e;
    e.x = exp2f(mv.x * LOG2E); e.y = exp2f(mv.y * LOG2E);
    e.z = exp2f(mv.z * LOG2E); e.w = exp2f(mv.w * LOG2E);
    ((float4*)mexpf)[j] = e;
    ushort4 ob;
    ob.x = f2bf(e.x); ob.y = f2bf(e.y); ob.z = f2bf(e.z); ob.w = f2bf(e.w);
    ((ushort4*)mexpb)[j] = ob;
    return;
  }
  const float* s; u16* d; int idx;
  if (i < 2097152) { s = hid; d = hb; idx = i; }
  else {
    int j = i - 2097152;
    int w = j >> 18; idx = j & 262143;
    if      (w == 0) { s = wq; d = wqkv; }
    else if (w == 1) { s = wk; d = wqkv + 1048576; }
    else if (w == 2) { s = wv; d = wqkv + 2097152; }
    else             { s = wo; d = wo_b; }
  }
  float4 v = ((const float4*)s)[idx];
  ushort4 o;
  o.x = f2bf(v.x); o.y = f2bf(v.y); o.z = f2bf(v.z); o.w = f2bf(v.w);
  ((ushort4*)d)[idx] = o;
}

// ---------------- bf16 NT GEMM (m97 structure) -----------------------------
// EPI=0: outb = bf16((acc + bias)*scale), scale = mexpf[row] for V cols
//        (folds the additive attention mask into V rows: softmax identity)
// EPI=1: outf = acc + b0 + resid
template<int EPI>
__global__ __launch_bounds__(256, 2) void gemm_bf16(
    const u16* __restrict__ A, const u16* __restrict__ B,
    u16* __restrict__ outb, float* __restrict__ outf, int ldc,
    const float* __restrict__ b0, const float* __restrict__ b1,
    const float* __restrict__ b2, const float* __restrict__ resid,
    const float* __restrict__ mexpf)
{
  __shared__ __align__(16) u16 As[128 * 32];
  __shared__ __align__(16) u16 Bs[128 * 32];
  const int tid = threadIdx.x;
  const int lane = tid & 63;
  const int wv = tid >> 6, wr = wv >> 1, wc = wv & 1;
  const int l15 = lane & 15, l4 = lane >> 4;

  const int nwg = gridDim.x * gridDim.y;
  const int flat = blockIdx.y * gridDim.x + blockIdx.x;
  const int swz = (flat & 7) * (nwg >> 3) + (flat >> 3);
  const int row0 = (swz / gridDim.x) * 128, col0 = (swz % gridDim.x) * 128;

  const f32x4 fz = {0.f, 0.f, 0.f, 0.f};
  f32x4 acc[4][4];
#pragma unroll
  for (int i = 0; i < 4; ++i)
#pragma unroll
    for (int j = 0; j < 4; ++j) acc[i][j] = fz;

  const int srow = lane >> 2;
  const int skol = (lane & 3) * 8;
  const u16* Ab = A + (size_t)(row0 + srow) * 1024 + skol;
  const u16* Bb = B + (size_t)(col0 + srow) * 1024 + skol;
  const int c0 = wv * 2;

  for (int kt = 0; kt < 1024; kt += 32) {
    gload16(Ab + (size_t)(c0 * 16) * 1024 + kt,       &As[(c0 * 16) * 32]);
    gload16(Ab + (size_t)(c0 * 16 + 16) * 1024 + kt,  &As[(c0 * 16 + 16) * 32]);
    gload16(Bb + (size_t)(c0 * 16) * 1024 + kt,       &Bs[(c0 * 16) * 32]);
    gload16(Bb + (size_t)(c0 * 16 + 16) * 1024 + kt,  &Bs[(c0 * 16 + 16) * 32]);
    __syncthreads();

    bf16x8 af[4], bfr[4];
#pragma unroll
    for (int f = 0; f < 4; ++f) {
      af[f]  = *(const bf16x8*)&As[(wr * 64 + f * 16 + l15) * 32 + l4 * 8];
      bfr[f] = *(const bf16x8*)&Bs[(wc * 64 + f * 16 + l15) * 32 + l4 * 8];
    }
#pragma unroll
    for (int i = 0; i < 4; ++i)
#pragma unroll
      for (int j = 0; j < 4; ++j)
        acc[i][j] = MFMA16(af[i], bfr[j], acc[i][j]);
    __syncthreads();
  }

  if (EPI == 0) {
    const float* bias = (col0 < 1024) ? b0 : (col0 < 2048) ? b1 : b2;
    const bool isv = (col0 >= 2048);
#pragma unroll
    for (int i = 0; i < 4; ++i) {
      int gr0 = row0 + wr * 64 + i * 16 + l4 * 4;
      float scl4[4];
#pragma unroll
      for (int r = 0; r < 4; ++r) scl4[r] = isv ? mexpf[gr0 + r] : 1.0f;
#pragma unroll
      for (int j = 0; j < 4; ++j) {
        int gc = col0 + wc * 64 + j * 16 + l15;
        float bv = bias[gc & 1023];
#pragma unroll
        for (int r = 0; r < 4; ++r)
          outb[(size_t)(gr0 + r) * ldc + gc] = f2bf((acc[i][j][r] + bv) * scl4[r]);
      }
    }
  } else {
#pragma unroll
    for (int i = 0; i < 4; ++i) {
      int gr0 = row0 + wr * 64 + i * 16 + l4 * 4;
#pragma unroll
      for (int j = 0; j < 4; ++j) {
        int gc = col0 + wc * 64 + j * 16 + l15;
        float bv = b0[gc];
#pragma unroll
        for (int r = 0; r < 4; ++r) {
          size_t idx = (size_t)(gr0 + r) * ldc + gc;
          outf[idx] = acc[i][j][r] + bv + resid[idx];
        }
      }
    }
  }
}

// ---------------- flash attention: swapped-QK 32x32, in-register softmax ----
// Mask hoisted out of the inner loop (V prescaled by mexp in the QKV
// epilogue; denominator = sum P*mexp via 4 extra MFMA32 with a mexp
// B-fragment). exp arg is a single fma exp2(s*SC - m); max3-friendly tree.
__global__ __launch_bounds__(256, 2) void flash_attn(
    const u16* __restrict__ qkv, const u16* __restrict__ mexpb,
    u16* __restrict__ ctxb)
{
  __shared__ __align__(16) u16 Qs[128 * 64];   // swizzled rows
  __shared__ __align__(16) u16 Ks[64 * 64];    // swizzled rows
  __shared__ __align__(16) u16 Vs[4096];       // subtiled

  const int flat = (blockIdx.z * 16 + blockIdx.y) * 16 + blockIdx.x;
  const int swzb = (flat & 7) * 128 + (flat >> 3);
  const int qt = swzb & 15, h = (swzb >> 4) & 15, b = swzb >> 8;

  const int tid = threadIdx.x, lane = tid & 63, wq = tid >> 6;
  const int l31 = lane & 31, l15 = lane & 15, h5 = lane >> 5;

  const size_t tokb = (size_t)b * SEQ;
  const u16* Qg = qkv + (tokb + (size_t)qt * 128) * QKVN + h * HD;
  const u16* Kg = qkv + tokb * QKVN + 1024 + h * HD;
  const u16* Vg = qkv + tokb * QKVN + 2048 + h * HD;
  const u16* Mg = mexpb + tokb;

  // ---- stage Q [128][64] swizzled ----
#pragma unroll
  for (int cc = 0; cc < 4; ++cc) {
    int c = tid + cc * 256;
    int r = c >> 3, ko = (c & 7) * 8;
    u32 qb = (u32)(r * 128 + ko * 2) ^ ((r & 7) << 4);
    *(uint4*)((char*)Qs + qb) = *(const uint4*)&Qg[(size_t)r * QKVN + ko];
  }
  __syncthreads();

  const u32 swzl = (u32)((l31 & 7) << 4);
  u32 cb[4];
#pragma unroll
  for (int kb = 0; kb < 4; ++kb)
    cb[kb] = ((u32)(kb * 32 + h5 * 16)) ^ swzl;

  // Q B-frags (col q = l31, k = 8*h5 + i per 16-k block kb)
  bf16x8 qf[4];
#pragma unroll
  for (int kb = 0; kb < 4; ++kb)
    qf[kb] = *(const bf16x8*)((char*)Qs + (u32)((wq * 32 + l31) * 128) + cb[kb]);

  float m_run = -1e30f;
  f32x16 ctx0 = {}, ctx1 = {}, lsum = {};

  // staging coords
  const int sr = tid >> 3, sk = (tid & 7) * 8;
  const u32 kwb0 = ((u32)(sr * 128 + sk * 2)) ^ ((sr & 7) << 4);
  const u32 kwb1 = ((u32)((sr + 32) * 128 + sk * 2)) ^ ((sr & 7) << 4);
  const u32 vw0 = (u32)((sk >> 4) * 1024 + (sr >> 2) * 64 + (sr & 3) * 16 + (sk & 15));
  const u32 vw1 = (u32)((sk >> 4) * 1024 + ((sr + 32) >> 2) * 64 + (sr & 3) * 16 + (sk & 15));

  const u32 vaddr = lds_addr(Vs) + (u32)(l15 * 8 + ((lane >> 4) & 1) * 2048 + h5 * 256);

  uint4 kr0 = *(const uint4*)&Kg[(size_t)sr * QKVN + sk];
  uint4 kr1 = *(const uint4*)&Kg[(size_t)(sr + 32) * QKVN + sk];
  uint4 vr0 = *(const uint4*)&Vg[(size_t)sr * QKVN + sk];
  uint4 vr1 = *(const uint4*)&Vg[(size_t)(sr + 32) * QKVN + sk];

  for (int kv0 = 0; kv0 < SEQ; kv0 += 64) {
    *(uint4*)((char*)Ks + kwb0) = kr0;
    *(uint4*)((char*)Ks + kwb1) = kr1;
    *(uint4*)&Vs[vw0] = vr0;
    *(uint4*)&Vs[vw1] = vr1;
    __syncthreads();

    // T14: next tile's global loads + this tile's mexp frags (latency hides)
    if (kv0 + 64 < SEQ) {
      kr0 = *(const uint4*)&Kg[(size_t)(kv0 + 64 + sr) * QKVN + sk];
      kr1 = *(const uint4*)&Kg[(size_t)(kv0 + 96 + sr) * QKVN + sk];
      vr0 = *(const uint4*)&Vg[(size_t)(kv0 + 64 + sr) * QKVN + sk];
      vr1 = *(const uint4*)&Vg[(size_t)(kv0 + 96 + sr) * QKVN + sk];
    }
    bf16x8 mf[4];
#pragma unroll
    for (int kb = 0; kb < 4; ++kb)
      mf[kb] = *(const bf16x8*)&Mg[kv0 + kb * 16 + 8 * h5];

    // ---- QK^T swapped: s = K_tile x Q^T, D[kv][q] ----
    f32x16 s0 = {}, s1 = {};
    __builtin_amdgcn_s_setprio(1);
#pragma unroll
    for (int kb = 0; kb < 4; ++kb) {
      bf16x8 a0 = *(const bf16x8*)((char*)Ks + (u32)(l31 * 128) + cb[kb]);
      bf16x8 a1 = *(const bf16x8*)((char*)Ks + (u32)(l31 * 128 + 4096) + cb[kb]);
      s0 = MFMA32(a0, qf[kb], s0);
      s1 = MFMA32(a1, qf[kb], s1);
    }
    __builtin_amdgcn_s_setprio(0);

    // ---- max over 32 raw scores (max3-friendly tree), then scale once ----
    float t0 = fmaxf(fmaxf(s0[0],  s0[1]),  s0[2]);
    float t1 = fmaxf(fmaxf(s0[3],  s0[4]),  s0[5]);
    float t2 = fmaxf(fmaxf(s0[6],  s0[7]),  s0[8]);
    float t3 = fmaxf(fmaxf(s0[9],  s0[10]), s0[11]);
    float t4 = fmaxf(fmaxf(s0[12], s0[13]), s0[14]);
    float t5 = fmaxf(fmaxf(s0[15], s1[0]),  s1[1]);
    float t6 = fmaxf(fmaxf(s1[2],  s1[3]),  s1[4]);
    float t7 = fmaxf(fmaxf(s1[5],  s1[6]),  s1[7]);
    float t8 = fmaxf(fmaxf(s1[8],  s1[9]),  s1[10]);
    float t9 = fmaxf(fmaxf(s1[11], s1[12]), s1[13]);
    float ta = fmaxf(s1[14], s1[15]);
    t0 = fmaxf(fmaxf(t0, t1), t2);
    t3 = fmaxf(fmaxf(t3, t4), t5);
    t6 = fmaxf(fmaxf(t6, t7), t8);
    t9 = fmaxf(t9, ta);
    float mxs = fmaxf(fmaxf(t0, t3), fmaxf(t6, t9)) * SC;
    mxs = fmaxf(mxs, __shfl_xor(mxs, 32));

    // defer-max (T13)
    bool need = (mxs > m_run + 11.5415603f);
    if (__any((int)need)) {
      float mn = fmaxf(m_run, mxs);
      float al = exp2f(m_run - mn);
      m_run = mn;
#pragma unroll
      for (int r = 0; r < 16; ++r) {
        float av = __shfl(al, (r & 3) + 8 * (r >> 2) + 4 * h5);
        ctx0[r] *= av;
        ctx1[r] *= av;
        lsum[r] *= av;
      }
    }

    // ---- exp (single fma arg) ----
#pragma unroll
    for (int r = 0; r < 16; ++r) s0[r] = exp2f(s0[r] * SC - m_run);
#pragma unroll
    for (int r = 0; r < 16; ++r) s1[r] = exp2f(s1[r] * SC - m_run);

    // ---- P -> bf16 A-frags (T12) ----
    bf16x8 paf[4];
#pragma unroll
    for (int blk = 0; blk < 4; ++blk) {
      u32 w0, w1, w2, w3;
      if (blk < 2) {
        int r0 = blk * 8;
        w0 = cvtpk(s0[r0 + 0], s0[r0 + 1]); w1 = cvtpk(s0[r0 + 2], s0[r0 + 3]);
        w2 = cvtpk(s0[r0 + 4], s0[r0 + 5]); w3 = cvtpk(s0[r0 + 6], s0[r0 + 7]);
      } else {
        int r0 = (blk - 2) * 8;
        w0 = cvtpk(s1[r0 + 0], s1[r0 + 1]); w1 = cvtpk(s1[r0 + 2], s1[r0 + 3]);
        w2 = cvtpk(s1[r0 + 4], s1[r0 + 5]); w3 = cvtpk(s1[r0 + 6], s1[r0 + 7]);
      }
      asm volatile("v_permlane32_swap_b32 %0, %1" : "+v"(w0), "+v"(w2));
      asm volatile("v_permlane32_swap_b32 %0, %1" : "+v"(w1), "+v"(w3));
      u32x4 ww = {w0, w1, w2, w3};
      paf[blk] = __builtin_bit_cast(bf16x8, ww);
    }

    // ---- denominator: lsum += P * mexp-frag (matrix pipe, idle anyway) ----
    __builtin_amdgcn_s_setprio(1);
#pragma unroll
    for (int kb = 0; kb < 4; ++kb)
      lsum = MFMA32(paf[kb], mf[kb], lsum);

    // ---- PV: ctx[db] += P * V, V via tr-read ----
#pragma unroll
    for (int db = 0; db < 2; ++db) {
      v2u t[8];
#pragma unroll
      for (int kb = 0; kb < 4; ++kb) {
        asm volatile("ds_read_b64_tr_b16 %0, %1 offset:%c2"
                     : "=&v"(t[kb * 2])     : "v"(vaddr), "i"(db * 4096 + kb * 512));
        asm volatile("ds_read_b64_tr_b16 %0, %1 offset:%c2"
                     : "=&v"(t[kb * 2 + 1]) : "v"(vaddr), "i"(db * 4096 + kb * 512 + 128));
      }
      asm volatile("s_waitcnt lgkmcnt(0)");
      __builtin_amdgcn_sched_barrier(0);
#pragma unroll
      for (int kb = 0; kb < 4; ++kb) {
        u32x4 ww = {t[kb * 2][0], t[kb * 2][1], t[kb * 2 + 1][0], t[kb * 2 + 1][1]};
        bf16x8 vf = __builtin_bit_cast(bf16x8, ww);
        if (db == 0) ctx0 = MFMA32(paf[kb], vf, ctx0);
        else         ctx1 = MFMA32(paf[kb], vf, ctx1);
      }
    }
    __builtin_amdgcn_s_setprio(0);
    __syncthreads();
  }

  // ---- extract denominator for own q (= l31) from lsum D-layout ----
  // row q lives in half (q>>2)&1 at reg with (r&3)+8*(r>>2) == q - 4*h5.
  float sel = 0.f;
  const int tt = l31 - 4 * h5;
#pragma unroll
  for (int r = 0; r < 16; ++r) {
    const int c = (r & 3) + 8 * (r >> 2);
    sel = (tt == c) ? lsum[r] : sel;
  }
  float pl = __shfl_xor(sel, 32);
  float lq = (((l31 >> 2) & 1) == h5) ? sel : pl;
  float linv = 1.0f / lq;

  // ---- normalize + write ----
#pragma unroll
  for (int r = 0; r < 16; ++r) {
    int qidx = (r & 3) + 8 * (r >> 2) + 4 * h5;
    float li = __shfl(linv, qidx);
    int gr = qt * 128 + wq * 32 + qidx;
    u16* o = &ctxb[(tokb + gr) * (size_t)H + h * HD + l31];
    o[0]  = f2bf(ctx0[r] * li);
    o[32] = f2bf(ctx1[r] * li);
  }
}

// ---------------- residual LayerNorm ----------------
__global__ __launch_bounds__(256) void ln_res(const float* __restrict__ x,
    const float* __restrict__ gamma, const float* __restrict__ beta,
    float* __restrict__ out)
{
  const int row = blockIdx.x, t = threadIdx.x;
  float4 v = ((const float4*)(x + (size_t)row * H))[t];
  float s1 = v.x + v.y + v.z + v.w;
  float s2 = v.x * v.x + v.y * v.y + v.z * v.z + v.w * v.w;
#pragma unroll
  for (int d = 1; d < 64; d <<= 1) { s1 += __shfl_xor(s1, d); s2 += __shfl_xor(s2, d); }
  __shared__ float a1[4], a2[4];
  if ((t & 63) == 0) { a1[t >> 6] = s1; a2[t >> 6] = s2; }
  __syncthreads();
  s1 = a1[0] + a1[1] + a1[2] + a1[3];
  s2 = a2[0] + a2[1] + a2[2] + a2[3];
  float mu  = s1 * (1.f / H);
  float var = s2 * (1.f / H) - mu * mu;
  float rstd = rsqrtf(var + 1e-12f);
  float4 g  = ((const float4*)gamma)[t];
  float4 be = ((const float4*)beta)[t];
  float4 o;
  o.x = (v.x - mu) * rstd * g.x + be.x;
  o.y = (v.y - mu) * rstd * g.y + be.y;
  o.z = (v.z - mu) * rstd * g.z + be.z;
  o.w = (v.w - mu) * rstd * g.w + be.w;
  ((float4*)(out + (size_t)row * H))[t] = o;
}

// ---------------- launch ----------------
extern "C" void kernel_launch(void* const* d_in, const int* in_sizes, int n_in,
                              void* d_out, int out_size, void* d_ws, size_t ws_size,
                              hipStream_t stream)
{
  const float* hid  = (const float*)d_in[0];
  const float* mask = (const float*)d_in[1];
  const float* Wq   = (const float*)d_in[2];
  const float* bq   = (const float*)d_in[3];
  const float* Wk   = (const float*)d_in[4];
  const float* bk   = (const float*)d_in[5];
  const float* Wv   = (const float*)d_in[6];
  const float* bv   = (const float*)d_in[7];
  const float* Wo   = (const float*)d_in[8];
  const float* bo   = (const float*)d_in[9];
  const float* gam  = (const float*)d_in[10];
  const float* bet  = (const float*)d_in[11];

  char* ws = (char*)d_ws;
  u16*   hb    = (u16*)(ws);               // hidden bf16   [8192][1024]
  u16*   wqkv  = (u16*)(ws + 16777216);    // Wq|Wk|Wv bf16 [3072][1024]
  u16*   wo_b  = (u16*)(ws + 23068672);    // Wo bf16       [1024][1024]
  u16*   qkvb  = (u16*)(ws + 25165824);    // QKV bf16      [8192][3072]
  u16*   ctxb  = (u16*)(ws + 75497472);    // ctx bf16      [8192][1024]
  float* mexpf = (float*)(ws + 92274688);  // exp2(mask*log2e) f32 [8192]
  u16*   mexpb = (u16*)(ws + 92307456);    // same, bf16 [8192]
  float* tmp   = (float*)(ws + 25165824);  // overlays qkvb (dead after attn)

  cast_all<<<12296, 256, 0, stream>>>(hid, Wq, Wk, Wv, Wo, mask,
                                      hb, wqkv, wo_b, mexpf, mexpb);

  gemm_bf16<0><<<dim3(24, 64), 256, 0, stream>>>(hb, wqkv, qkvb, nullptr, QKVN,
                                                 bq, bk, bv, nullptr, mexpf);
  flash_attn<<<dim3(16, NH, BATCH), 256, 0, stream>>>(qkvb, mexpb, ctxb);
  gemm_bf16<1><<<dim3(8, 64), 256, 0, stream>>>(ctxb, wo_b, nullptr, tmp, H,
                                                bo, nullptr, nullptr, hid, nullptr);
  ln_res<<<8192, 256, 0, stream>>>(tmp, gam, bet, (float*)d_out);
}